// Round 8
// baseline (504.066 us; speedup 1.0000x reference)
//
// AttentionPropagation — fused bf16-MFMA flash attention for MI355X (gfx950).
//
// R8 (theory: latency-bound on barriers+LDS at 1 wave/SIMD; R3's 8-wave TLP
// beat R6/R7's halved-LDS-traffic — so remove the latency source entirely):
//  * ZERO-LDS attn: prep_kv stores K and V^T as fragment-major MFMA operands
//    (K via conv8 — the same C-layout->fragment transform verified on Q/P/
//    epilogue; V^T via an 8KB wave-local LDS transpose inside prep).
//  * attn_fwd: no __shared__, no __syncthreads. 17 coalesced 1KB global loads
//    per tile (L2-resident 4.25MB), double-buffered in registers, prefetched
//    one tile ahead. 64-thread blocks x 1024 — fully independent waves.
//  * Deferred-PV pipeline kept (PV(t-1) inside iter t); loop parity-unrolled
//    x2 so all buffer indices are compile-time (no scratch).
//  * s_setprio removed (1 wave/SIMD: nothing to arbitrate).
// Math identical to R7 (passed, absmax 0.015625): 64q/wave dual groups,
// q2-folded bias MFMA, exp2 softmax, defer-max, cvt_pk, shfl_xor(32) conv8.

#include <hip/hip_runtime.h>
#include <stdint.h>

#define NB 2
#define N1 4096
#define N2 32768
#define DD 128
#define KT 32
#define NTILES (N1 / KT)
static constexpr float SCLE = 0.1275174306f;         // 128^-0.5 * log2(e)
static constexpr float CNEG = -0.7213475204444817f;  // -0.5 * log2(e)
static constexpr float THR  = 11.5415603f;           // 8 * log2(e) (defer-max)

typedef float f32x16 __attribute__((ext_vector_type(16)));
typedef __bf16 bf16x8v __attribute__((ext_vector_type(8)));
typedef __bf16 bf16x2v __attribute__((ext_vector_type(2)));
typedef unsigned int u32;
typedef unsigned short u16;

union FragU { uint4 u; bf16x8v b; };

__device__ __forceinline__ u16 f2bf(float f) {
  __bf16 h = (__bf16)f;
  return __builtin_bit_cast(u16, h);
}
__device__ __forceinline__ u32 pk2(float lo, float hi) {
  bf16x2v v; v[0] = (__bf16)lo; v[1] = (__bf16)hi;  // v_cvt_pk_bf16_f32
  return __builtin_bit_cast(u32, v);
}
__device__ __forceinline__ float bfhi(float f) { return (float)(__bf16)f; }
__device__ __forceinline__ float m3(float a, float b, float c) {
  return fmaxf(fmaxf(a, b), c);                      // v_max3_f32
}
__device__ __forceinline__ f32x16 MFMA(uint4 a, uint4 b, const f32x16& c) {
  FragU A, B; A.u = a; B.u = b;
  return __builtin_amdgcn_mfma_f32_32x32x16_bf16(A.b, B.b, c, 0, 0, 0);
}
__device__ __forceinline__ uint4 packhi8(float4 a, float4 b) {
  return make_uint4(pk2(a.x, a.y), pk2(a.z, a.w), pk2(b.x, b.y), pk2(b.z, b.w));
}
__device__ __forceinline__ uint4 packlo8(float4 a, float4 b) {
  return make_uint4(pk2(a.x - bfhi(a.x), a.y - bfhi(a.y)),
                    pk2(a.z - bfhi(a.z), a.w - bfhi(a.w)),
                    pk2(b.x - bfhi(b.x), b.y - bfhi(b.y)),
                    pk2(b.z - bfhi(b.z), b.w - bfhi(b.w)));
}
// C-layout 8-chunk -> MFMA fragment (K=16).  Works for BOTH B-frags (lane=col)
// and A-frags (lane=row): element layout is identical — lane l gets the 8
// consecutive k-rows 8*(l>>5)+j of its own C column, via shfl_xor(32) partner
// exchange.  (Verified end-to-end on Q, P, epilogue since R1; K-frag use in
// prep_kv is the A-frag instance.)
__device__ __forceinline__ uint4 conv8(float a0, float a1, float a2, float a3,
                                       float a4, float a5, float a6, float a7, int h) {
  u32 A0 = pk2(a0, a1), A1 = pk2(a2, a3);
  u32 B0 = pk2(a4, a5), B1 = pk2(a6, a7);
  u32 A0s = (u32)__shfl_xor((int)A0, 32);
  u32 A1s = (u32)__shfl_xor((int)A1, 32);
  u32 B0s = (u32)__shfl_xor((int)B0, 32);
  u32 B1s = (u32)__shfl_xor((int)B1, 32);
  return h ? make_uint4(B0s, B1s, B0, B1) : make_uint4(A0, A1, A0s, A1s);
}

// ---------------------------------------------------------------------------
// prep_kv: 256 blocks x 32 keys (1 key-tile each); 4 waves split out-dims.
// Emits fragment-major Kf / Vf (uint4 per lane) + extK.
//   Kf[((b*NTILES+t)*8 + kk)*64 + l] : K-tile A-frag, d-window [16kk,16kk+16)
//   Vf[((b*NTILES+t)*8 + 2*ft+s)*64 + l] : V^T A-frag, f-rows [32ft,32ft+32),
//                                          key-window [16s,16s+16)
// ---------------------------------------------------------------------------
__global__ __launch_bounds__(256) void prep_kv(
    const float* __restrict__ sxyz, const float* __restrict__ sfeat,
    const float* __restrict__ Wk, const float* __restrict__ bk,
    const float* __restrict__ Wv, const float* __restrict__ bv,
    uint4* __restrict__ Kf, uint4* __restrict__ Vf, u16* __restrict__ EKws) {
  __shared__ __align__(16) u16 sv[128 * 32];   // V^T transpose scratch [o][key]
  const int tid = threadIdx.x;
  const int l = tid & 63, w = tid >> 6, h = l >> 5, ln = l & 31;
  const int b = blockIdx.x >> 7;             // 128 blocks per batch
  const int tile = blockIdx.x & 127;
  const int kb = tile * 32;
  const int key = kb + ln;
  const size_t frow = (size_t)(b * N1 + key) * DD;

  uint4 xf[8];
#pragma unroll
  for (int s = 0; s < 8; ++s) {
    const float4* fp = (const float4*)(sfeat + frow + s * 16 + h * 8);
    xf[s] = packhi8(fp[0], fp[1]);
  }
  const float* xp = sxyz + (size_t)(b * N1 + key) * 3;
  float sx = xp[0], sy = xp[1], sz = xp[2];
  uint4 x8 = h ? make_uint4(0, 0, 0, 0)
               : make_uint4(pk2(sx, sy), pk2(sz, 0.f), 0u, 0u);

  f32x16 kacc, vacc;
#pragma unroll
  for (int r = 0; r < 16; ++r) {
    int o = (r & 3) + 8 * (r >> 2) + 4 * h + 32 * w;
    kacc[r] = bk[o];
    vacc[r] = bv[o];
  }

  const int outd = ln + 32 * w;
  const float* wkr = Wk + (size_t)outd * 131;
  const float* wvr = Wv + (size_t)outd * DD;
#pragma unroll
  for (int s = 0; s < 8; ++s) {
    const float* p = wkr + 3 + s * 16 + h * 8;   // feat weights at cols 3..130
    uint4 wa = make_uint4(pk2(p[0], p[1]), pk2(p[2], p[3]),
                          pk2(p[4], p[5]), pk2(p[6], p[7]));
    kacc = MFMA(wa, xf[s], kacc);
    const float4* q = (const float4*)(wvr + s * 16 + h * 8);
    vacc = MFMA(packhi8(q[0], q[1]), xf[s], vacc);
  }
  {
    uint4 w8 = h ? make_uint4(0, 0, 0, 0)
                 : make_uint4(pk2(wkr[0], wkr[1]), pk2(wkr[2], 0.f), 0u, 0u);
    kacc = MFMA(w8, x8, kacc);
  }

  // ---- K fragments: kacc C-layout (col=key=lane) -> A-frags via conv8.
  const size_t fbase = ((size_t)(b * NTILES + tile)) * 8;
  {
    uint4 kf0 = conv8(kacc[0], kacc[1], kacc[2], kacc[3],
                      kacc[4], kacc[5], kacc[6], kacc[7], h);      // kk = 2w
    uint4 kf1 = conv8(kacc[8], kacc[9], kacc[10], kacc[11],
                      kacc[12], kacc[13], kacc[14], kacc[15], h);  // kk = 2w+1
    Kf[(fbase + 2 * w + 0) * 64 + l] = kf0;
    Kf[(fbase + 2 * w + 1) * 64 + l] = kf1;
  }

  // ---- V^T fragments: transpose vacc (lane=key) to f-major via LDS.
  // Wave w writes and reads only rows o in [32w, 32w+32) — no barrier needed.
#pragma unroll
  for (int r = 0; r < 16; ++r) {
    int o = (r & 3) + 8 * (r >> 2) + 4 * h + 32 * w;
    sv[o * 32 + ln] = f2bf(vacc[r]);
  }
#pragma unroll
  for (int s = 0; s < 2; ++s) {
    uint4 va = *(const uint4*)&sv[(32 * w + ln) * 32 + 16 * s + 8 * h];
    Vf[(fbase + 2 * w + s) * 64 + l] = va;
  }

  // extK pairs with extQ: sum = |k|^2 - 2 q.k + |q|^2 (1.0 slots carry q2h/q2l)
  if (tid < 32) {
    int k2i = kb + tid;
    const float* xq = sxyz + (size_t)(b * N1 + k2i) * 3;
    float x = xq[0], y = xq[1], z = xq[2];
    float k2 = x * x + y * y + z * z;
    float xh = bfhi(x), xl = x - xh;
    float yh = bfhi(y), yl = y - yh;
    float zh = bfhi(z), zl = z - zh;
    float k2h = bfhi(k2), k2l = k2 - k2h;
    uint4 e0 = make_uint4(pk2(xh, xl), pk2(xh, yh), pk2(yl, yh), pk2(zh, zl));
    uint4 e1 = make_uint4(pk2(zh, k2h), pk2(k2l, 1.f), pk2(1.f, 0.f), 0u);
    uint4* dst = (uint4*)&EKws[(size_t)(b * N1 + k2i) * 16];
    dst[0] = e0;
    dst[1] = e1;
  }
}

// ---------------------------------------------------------------------------
// attn_fwd: 64-thread blocks (1 wave, 64 queries), zero LDS, zero barriers.
// Fragments streamed from L2 into double-buffered registers.
// ---------------------------------------------------------------------------
__global__ __launch_bounds__(64, 1) void attn_fwd(
    const float* __restrict__ dxyz, const float* __restrict__ dfeat,
    const float* __restrict__ Wq, const float* __restrict__ bq,
    const float* __restrict__ Wo, const float* __restrict__ bo,
    const uint4* __restrict__ Kf, const uint4* __restrict__ Vf,
    const u16* __restrict__ EKws, float* __restrict__ out) {
  const int l = threadIdx.x, ln = l & 31, h = l >> 5;
  const int b = blockIdx.x >> 9;             // 512 blocks per batch
  const int qb = (blockIdx.x & 511) * 64;
  const int bN1 = b * N1;
  size_t qrow[2];
  qrow[0] = (size_t)(b * N2 + qb + ln);
  qrow[1] = qrow[0] + 32;

  f32x16 zf;
#pragma unroll
  for (int r = 0; r < 16; ++r) zf[r] = 0.f;

  // ---- extQ per group (q2 split-folded into the MFMA via extK's 1.0 slots)
  uint4 eq[2];
  float qx[2], qy[2], qz[2];
#pragma unroll
  for (int g = 0; g < 2; ++g) {
    const float* xp = dxyz + qrow[g] * 3;
    float x = xp[0], y = xp[1], z = xp[2];
    float q2 = x * x + y * y + z * z;
    float xh = bfhi(x), xl = x - xh, yh = bfhi(y), yl = y - yh, zh = bfhi(z), zl = z - zh;
    float q2h = bfhi(q2), q2l = q2 - q2h;
    eq[g] = h ? make_uint4(pk2(-2.f * zl, 1.f), pk2(1.f, q2h), pk2(q2l, 0.f), 0u)
              : make_uint4(pk2(-2.f * xh, -2.f * xh), pk2(-2.f * xl, -2.f * yh),
                           pk2(-2.f * yh, -2.f * yl), pk2(-2.f * zh, -2.f * zh));
    qx[g] = x; qy[g] = y; qz[g] = z;
  }

  // ---- Q projection (pre-scaled by SCALE*log2e); W packs shared by groups
  uint4 qf[2][8];
  {
    uint4 xf[2][8], x8[2];
#pragma unroll
    for (int g = 0; g < 2; ++g) {
#pragma unroll
      for (int s = 0; s < 8; ++s) {
        const float4* fp = (const float4*)(dfeat + qrow[g] * DD + s * 16 + h * 8);
        xf[g][s] = packhi8(fp[0], fp[1]);
      }
      x8[g] = h ? make_uint4(0, 0, 0, 0)
                : make_uint4(pk2(qx[g], qy[g]), pk2(qz[g], 0.f), 0u, 0u);
    }
#pragma unroll
    for (int ot = 0; ot < 4; ++ot) {
      f32x16 qt[2];
#pragma unroll
      for (int r = 0; r < 16; ++r) {
        float bqv = SCLE * bq[(r & 3) + 8 * (r >> 2) + 4 * h + 32 * ot];
        qt[0][r] = bqv; qt[1][r] = bqv;
      }
      const float* wqr = Wq + (size_t)(ln + 32 * ot) * 131;
#pragma unroll
      for (int s = 0; s < 8; ++s) {
        const float* p = wqr + 3 + s * 16 + h * 8;
        uint4 wa = make_uint4(pk2(SCLE * p[0], SCLE * p[1]), pk2(SCLE * p[2], SCLE * p[3]),
                              pk2(SCLE * p[4], SCLE * p[5]), pk2(SCLE * p[6], SCLE * p[7]));
        qt[0] = MFMA(wa, xf[0][s], qt[0]);
        qt[1] = MFMA(wa, xf[1][s], qt[1]);
      }
      uint4 w8 = h ? make_uint4(0, 0, 0, 0)
                   : make_uint4(pk2(SCLE * wqr[0], SCLE * wqr[1]), pk2(SCLE * wqr[2], 0.f), 0u, 0u);
      qt[0] = MFMA(w8, x8[0], qt[0]);
      qt[1] = MFMA(w8, x8[1], qt[1]);
#pragma unroll
      for (int g = 0; g < 2; ++g) {
        qf[g][2 * ot] = conv8(qt[g][0], qt[g][1], qt[g][2], qt[g][3],
                              qt[g][4], qt[g][5], qt[g][6], qt[g][7], h);
        qf[g][2 * ot + 1] = conv8(qt[g][8], qt[g][9], qt[g][10], qt[g][11],
                                  qt[g][12], qt[g][13], qt[g][14], qt[g][15], h);
      }
    }
  }

  f32x16 oacc[2][4];
#pragma unroll
  for (int g = 0; g < 2; ++g)
#pragma unroll
    for (int ft = 0; ft < 4; ++ft)
#pragma unroll
      for (int r = 0; r < 16; ++r) oacc[g][ft][r] = 0.f;
  float m[2] = {-1e30f, -1e30f}, lsum[2] = {0.f, 0.f};

  const uint4* Kfb = Kf + (size_t)b * NTILES * 8 * 64;
  const uint4* Vfb = Vf + (size_t)b * NTILES * 8 * 64;
  const uint4* EK4 = (const uint4*)EKws;   // [key][2] frags of 16B

  uint4 kbuf[2][8], vbuf[2][8], ekb[2];
  uint4 pf[2][2];

#define LOADF(BUF, t_)                                                        \
  do {                                                                        \
    _Pragma("unroll")                                                         \
    for (int f_ = 0; f_ < 8; ++f_) {                                          \
      kbuf[BUF][f_] = Kfb[((size_t)(t_) * 8 + f_) * 64 + l];                  \
      vbuf[BUF][f_] = Vfb[((size_t)(t_) * 8 + f_) * 64 + l];                  \
    }                                                                         \
    ekb[BUF] = EK4[((size_t)(bN1 + (t_) * KT + ln)) * 2 + h];                 \
  } while (0)

#define ITER(t_, CUR, NXT)                                                    \
  {                                                                           \
    f32x16 sacc[2];                                                           \
    sacc[0] = MFMA(ekb[CUR], eq[0], zf);                                      \
    sacc[1] = MFMA(ekb[CUR], eq[1], zf);                                      \
    _Pragma("unroll")                                                         \
    for (int g = 0; g < 2; ++g)                                               \
      _Pragma("unroll")                                                       \
      for (int r = 0; r < 16; ++r)                                            \
        sacc[g][r] = CNEG * __builtin_amdgcn_sqrtf(fmaxf(sacc[g][r], 0.f));   \
    if ((t_) > 0) {       /* PV(t-1) from vbuf[NXT] — fills MFMA pipe */      \
      _Pragma("unroll")                                                       \
      for (int ft = 0; ft < 4; ++ft) {                                        \
        oacc[0][ft] = MFMA(vbuf[NXT][2 * ft], pf[0][0], oacc[0][ft]);         \
        oacc[1][ft] = MFMA(vbuf[NXT][2 * ft], pf[1][0], oacc[1][ft]);         \
        oacc[0][ft] = MFMA(vbuf[NXT][2 * ft + 1], pf[0][1], oacc[0][ft]);     \
        oacc[1][ft] = MFMA(vbuf[NXT][2 * ft + 1], pf[1][1], oacc[1][ft]);     \
      }                                                                       \
    }                                                                         \
    if ((t_) + 1 < NTILES) LOADF(NXT, (t_) + 1);                              \
    _Pragma("unroll")     /* QK(t) from kbuf[CUR] */                          \
    for (int kk = 0; kk < 8; ++kk) {                                          \
      sacc[0] = MFMA(kbuf[CUR][kk], qf[0][kk], sacc[0]);                      \
      sacc[1] = MFMA(kbuf[CUR][kk], qf[1][kk], sacc[1]);                      \
    }                                                                         \
    _Pragma("unroll")     /* online softmax + P-frag conversion */            \
    for (int g = 0; g < 2; ++g) {                                             \
      float a0 = m3(sacc[g][0], sacc[g][1], sacc[g][2]);                      \
      float a1 = m3(sacc[g][3], sacc[g][4], sacc[g][5]);                      \
      float a2 = m3(sacc[g][6], sacc[g][7], sacc[g][8]);                      \
      float a3 = m3(sacc[g][9], sacc[g][10], sacc[g][11]);                    \
      float a4 = m3(sacc[g][12], sacc[g][13], sacc[g][14]);                   \
      float tmax = fmaxf(m3(m3(a0, a1, a2), a3, a4), sacc[g][15]);            \
      tmax = fmaxf(tmax, __shfl_xor(tmax, 32));                               \
      if (!__all(tmax <= m[g] + THR)) {                                       \
        float nm = fmaxf(m[g], tmax);                                         \
        float fr = __builtin_amdgcn_exp2f(m[g] - nm);                         \
        lsum[g] *= fr;                                                        \
        _Pragma("unroll")                                                     \
        for (int ft = 0; ft < 4; ++ft)                                        \
          _Pragma("unroll")                                                   \
          for (int r = 0; r < 16; ++r) oacc[g][ft][r] *= fr;                  \
        m[g] = nm;                                                            \
      }                                                                       \
      _Pragma("unroll")                                                       \
      for (int r = 0; r < 16; ++r)                                            \
        sacc[g][r] = __builtin_amdgcn_exp2f(sacc[g][r] - m[g]);               \
      {                                                                       \
        float s0 = sacc[g][0] + sacc[g][1],   s1 = sacc[g][2] + sacc[g][3];   \
        float s2 = sacc[g][4] + sacc[g][5],   s3 = sacc[g][6] + sacc[g][7];   \
        float s4 = sacc[g][8] + sacc[g][9],   s5 = sacc[g][10] + sacc[g][11]; \
        float s6 = sacc[g][12] + sacc[g][13], s7 = sacc[g][14] + sacc[g][15]; \
        lsum[g] += (s0 + s1) + (s2 + s3) + ((s4 + s5) + (s6 + s7));           \
      }                                                                       \
      pf[g][0] = conv8(sacc[g][0], sacc[g][1], sacc[g][2], sacc[g][3],        \
                       sacc[g][4], sacc[g][5], sacc[g][6], sacc[g][7], h);    \
      pf[g][1] = conv8(sacc[g][8], sacc[g][9], sacc[g][10], sacc[g][11],      \
                       sacc[g][12], sacc[g][13], sacc[g][14], sacc[g][15], h);\
    }                                                                         \
  }

  LOADF(0, 0);
  for (int t = 0; t < NTILES; t += 2) {
    ITER(t, 0, 1);
    ITER(t + 1, 1, 0);
  }
  // drain: PV(NTILES-1) from vbuf[1] ((NTILES-1)&1 == 1)
#pragma unroll
  for (int ft = 0; ft < 4; ++ft) {
    oacc[0][ft] = MFMA(vbuf[1][2 * ft], pf[0][0], oacc[0][ft]);
    oacc[1][ft] = MFMA(vbuf[1][2 * ft], pf[1][0], oacc[1][ft]);
    oacc[0][ft] = MFMA(vbuf[1][2 * ft + 1], pf[0][1], oacc[0][ft]);
    oacc[1][ft] = MFMA(vbuf[1][2 * ft + 1], pf[1][1], oacc[1][ft]);
  }
#undef LOADF
#undef ITER

  // ---- epilogue: out^T = Wo·(O/l) + Wo_h·feat_h + Wo_h·feat_l + Wo_l·feat_h + bo
#pragma unroll
  for (int g = 0; g < 2; ++g) {
    lsum[g] += __shfl_xor(lsum[g], 32);
    const float inv = 1.f / lsum[g];
#pragma unroll
    for (int ft = 0; ft < 4; ++ft)
#pragma unroll
      for (int r = 0; r < 16; ++r) oacc[g][ft][r] *= inv;
  }

  f32x16 oc[2][4];
#pragma unroll
  for (int g = 0; g < 2; ++g)
#pragma unroll
    for (int ot = 0; ot < 4; ++ot)
#pragma unroll
      for (int r = 0; r < 16; ++r)
        oc[g][ot][r] = bo[(r & 3) + 8 * (r >> 2) + 4 * h + 32 * ot];

#pragma unroll
  for (int s = 0; s < 8; ++s) {
    uint4 pb[2], fh[2], fl[2];
#pragma unroll
    for (int g = 0; g < 2; ++g) {
      const f32x16& c = oacc[g][s >> 1];
      const int br = (s & 1) * 8;
      pb[g] = conv8(c[br + 0], c[br + 1], c[br + 2], c[br + 3],
                    c[br + 4], c[br + 5], c[br + 6], c[br + 7], h);
      const float4* fp = (const float4*)(dfeat + qrow[g] * DD + s * 16 + h * 8);
      const float4 fa = fp[0], fb = fp[1];
      fh[g] = packhi8(fa, fb);
      fl[g] = packlo8(fa, fb);
    }
#pragma unroll
    for (int ot = 0; ot < 4; ++ot) {
      const float4* wp = (const float4*)(Wo + (size_t)(ln + 32 * ot) * DD + s * 16 + h * 8);
      const float4 wa = wp[0], wb = wp[1];
      const uint4 wh = packhi8(wa, wb);
      const uint4 wl = packlo8(wa, wb);
#pragma unroll
      for (int g = 0; g < 2; ++g) {
        oc[g][ot] = MFMA(wh, pb[g], oc[g][ot]);
        oc[g][ot] = MFMA(wh, fh[g], oc[g][ot]);
        oc[g][ot] = MFMA(wh, fl[g], oc[g][ot]);
        oc[g][ot] = MFMA(wl, fh[g], oc[g][ot]);
      }
    }
  }

#pragma unroll
  for (int g = 0; g < 2; ++g) {
    float* orow = out + qrow[g] * DD;
#pragma unroll
    for (int ot = 0; ot < 4; ++ot)
#pragma unroll
      for (int rq = 0; rq < 4; ++rq)
        *(float4*)&orow[ot * 32 + rq * 8 + h * 4] =
            make_float4(oc[g][ot][rq * 4 + 0], oc[g][ot][rq * 4 + 1],
                        oc[g][ot][rq * 4 + 2], oc[g][ot][rq * 4 + 3]);
  }
}

// ---------------------------------------------------------------------------
extern "C" void kernel_launch(void* const* d_in, const int* in_sizes, int n_in,
                              void* d_out, int out_size, void* d_ws, size_t ws_size,
                              hipStream_t stream) {
  const float* sxyz = (const float*)d_in[0];
  const float* sfeat = (const float*)d_in[1];
  const float* dxyz = (const float*)d_in[2];
  const float* dfeat = (const float*)d_in[3];
  const float* Wq = (const float*)d_in[4];
  const float* bq = (const float*)d_in[5];
  const float* Wk = (const float*)d_in[6];
  const float* bk = (const float*)d_in[7];
  const float* Wv = (const float*)d_in[8];
  const float* bv = (const float*)d_in[9];
  const float* Wo = (const float*)d_in[10];
  const float* bo = (const float*)d_in[11];

  uint4* Kf = (uint4*)d_ws;                             // NB*128*8*64 uint4 = 2MB
  uint4* Vf = Kf + (size_t)NB * NTILES * 8 * 64;        // 2MB
  u16* EKws = (u16*)(Vf + (size_t)NB * NTILES * 8 * 64);// NB*N1*16 bf16 = 256KB

  prep_kv<<<dim3(NB * 128), dim3(256), 0, stream>>>(sxyz, sfeat, Wk, bk, Wv, bv,
                                                    Kf, Vf, EKws);
  attn_fwd<<<dim3(NB * 512), dim3(64), 0, stream>>>(dxyz, dfeat, Wq, bq, Wo, bo,
                                                    Kf, Vf, EKws, (float*)d_out);
}